// Round 2
// baseline (179.920 us; speedup 1.0000x reference)
//
#include <hip/hip_runtime.h>

// DynamicMaskHead fused v6 (MI355X / gfx950)
// pack_kernel: mask_feats (4,8,128,128) -> rec (4,16384,8) pixel-major in ws.
// dmh_kernel: grid = n_inst x 8 row-groups. Block computes logits rows
//   [16rg, 16rg+15] (NO halo in LDS: 16x128 tile = 8192 B -> 8 blocks/CU
//   under the 64KB occupancy LDS pool; v5's 16.9KB tile gave 3 blocks = 38%).
//   Halo row 16rg-1 (needed only for output row Y=32rg) is computed into
//   wave-0 registers (2 px/lane via shared-weight pair-MLP) and consumed
//   directly in wave-0's phase-B j=0 iteration; col-1 neighbor via shfl_up.
//   Parity-split LDS, factor-2 aligned_bilinear closed form, float4 stores.
//
// aligned_bilinear(factor=2): odd Y -> copy logits row (Y-1)/2; even Y ->
// avg rows (Y/2-1, Y/2); Y=0 via clamped halo (rh=max(16rg-1,0)). Same in
// X: out[4l..4l+3] from logits cols {2l-1, 2l, 2l+1}, col -1 clamped.

#define HW 16384
#define NP 169

__global__ __launch_bounds__(256)
void pack_kernel(const float* __restrict__ mf, float* __restrict__ rec)
{
    const int g   = blockIdx.x * 256 + threadIdx.x;   // 0..65535
    const int img = g >> 14;
    const int p   = g & 16383;
    const float* fb = mf + (size_t)img * 8 * HW + p;
    float4 a = make_float4(fb[0],      fb[HW],     fb[2 * HW], fb[3 * HW]);
    float4 b = make_float4(fb[4 * HW], fb[5 * HW], fb[6 * HW], fb[7 * HW]);
    float4* o = (float4*)(rec + (size_t)g * 8);
    o[0] = a;
    o[1] = b;
}

__global__ __launch_bounds__(256, 8)
void dmh_kernel(const float* __restrict__ mask_feats,   // (4,8,128,128)
                const float* __restrict__ mask_shift,   // (16384,2)
                const float* __restrict__ shifts,       // (n,2)
                const float* __restrict__ inst_params,  // (n,169)
                const int*   __restrict__ im_inds,      // (n,)
                const int*   __restrict__ fpn_levels,   // (n,)
                const float* __restrict__ rec,          // (4,16384,8) or null
                float*       __restrict__ out,          // (n,1,256,256)
                int use_rec)
{
    __shared__ float lgE[16 * 64];   // even cols of 16x128 logits tile
    __shared__ float lgO[16 * 64];   // odd cols

    const int bx   = blockIdx.x;
    const int inst = bx >> 3;
    const int rg   = bx & 7;
    const int tid  = threadIdx.x;
    const int r0   = rg * 16;        // first logits row of this block

    const int img = im_inds[inst];
    const float* __restrict__ wp = inst_params + (size_t)inst * NP;
    const float s0  = shifts[2 * inst];
    const float s1  = shifts[2 * inst + 1];
    const float inv = 1.0f / (float)(64 << fpn_levels[inst]);
    const float* __restrict__ fb = mask_feats + (size_t)img * 8 * HW;
    const float* __restrict__ rb = rec + (size_t)img * 8 * HW;

    // load MLP input for GLOBAL pixel index g (row*128+col)
    auto load_g = [&](int g, float* x) {
        const float2 ms = *(const float2*)(mask_shift + 2 * g);
        x[0] = (s0 - ms.x) * inv;
        x[1] = (s1 - ms.y) * inv;
        if (use_rec) {
            const float4* q = (const float4*)(rb + (size_t)g * 8);
            const float4 a = q[0], b = q[1];
            x[2] = a.x; x[3] = a.y; x[4] = a.z; x[5] = a.w;
            x[6] = b.x; x[7] = b.y; x[8] = b.z; x[9] = b.w;
        } else {
            #pragma unroll
            for (int k = 0; k < 8; ++k) x[2 + k] = fb[k * HW + g];
        }
    };

    // shared-weight pair MLP: two pixels -> two logits
    auto mlp2 = [&](const float* xa, const float* xb, float& va, float& vb) {
        float ya[8], yb[8];
        #pragma unroll
        for (int o = 0; o < 8; ++o) {
            const float bia = wp[152 + o];
            float a = bia, b = bia;
            #pragma unroll
            for (int c = 0; c < 10; ++c) {
                const float w = wp[o * 10 + c];
                a = fmaf(w, xa[c], a);
                b = fmaf(w, xb[c], b);
            }
            ya[o] = fmaxf(a, 0.f);
            yb[o] = fmaxf(b, 0.f);
        }
        float za[8], zb[8];
        #pragma unroll
        for (int o = 0; o < 8; ++o) {
            const float bia = wp[160 + o];
            float a = bia, b = bia;
            #pragma unroll
            for (int c = 0; c < 8; ++c) {
                const float w = wp[80 + o * 8 + c];
                a = fmaf(w, ya[c], a);
                b = fmaf(w, yb[c], b);
            }
            za[o] = fmaxf(a, 0.f);
            zb[o] = fmaxf(b, 0.f);
        }
        float a = wp[168], b = a;
        #pragma unroll
        for (int c = 0; c < 8; ++c) {
            const float w = wp[144 + c];
            a = fmaf(w, za[c], a);
            b = fmaf(w, zb[c], b);
        }
        va = a;
        vb = b;
    };

    // ---- phase A: 16x128 tile, 2048 px = exactly 4 pair-calls ----
    const int gbase = r0 << 7;       // r0*128
    #pragma unroll
    for (int u = 0; u < 4; ++u) {
        const int pA = tid + 512 * u;      // tile px 0..2047
        const int pB = pA + 256;
        float xa[10], xb[10];
        load_g(gbase + pA, xa);
        load_g(gbase + pB, xb);
        float va, vb;
        mlp2(xa, xb, va, vb);
        // tile px p -> parity-split LDS: idx = p>>1, parity = p&1
        if (pA & 1) { lgO[pA >> 1] = va; lgO[pB >> 1] = vb; }
        else        { lgE[pA >> 1] = va; lgE[pB >> 1] = vb; }
    }

    // ---- wave-0 halo: logits row rh = max(r0-1, 0), kept in registers ----
    float hE = 0.f, hO = 0.f, hM = 0.f;
    if (tid < 64) {
        const int gh = max(r0 - 1, 0) << 7;
        float xa[10], xb[10];
        load_g(gh + 2 * tid,     xa);      // even col 2l
        load_g(gh + 2 * tid + 1, xb);      // odd col 2l+1
        mlp2(xa, xb, hE, hO);
        const float sh = __shfl_up(hO, 1); // col 2l-1 from lane l-1
        hM = (tid == 0) ? hE : sh;         // col -1 clamps to col 0
    }

    __syncthreads();

    // ---- phase B: 32 output rows (Y = 32rg .. 32rg+31) x 256 cols ----
    float* __restrict__ op =
        out + (size_t)inst * 65536 + (size_t)(2 * r0) * 256;
    const int w = tid >> 6;
    const int l = tid & 63;
    const int parity = w & 1;        // wave-uniform row parity

    #pragma unroll
    for (int j = 0; j < 8; ++j) {
        const int p2 = (w >> 1) + 2 * j;     // 0..15
        const int yl = 2 * p2 + parity;      // 0..31
        float4 res;
        if (parity) {                // odd row: copy logits local row p2
            const float* e = lgE + p2 * 64;
            const float* o = lgO + p2 * 64;
            const float v0 = e[l];
            const float v1 = o[l];
            const float vm = (l > 0) ? o[l - 1] : v0;
            res = make_float4(0.5f * (vm + v0), v0, 0.5f * (v0 + v1), v1);
        } else {                     // even row: avg local rows p2-1, p2
            float v0A, v1A, vmA;
            if (p2 == 0) {           // only wave 0, j=0: halo from registers
                v0A = hE; v1A = hO; vmA = hM;
            } else {
                const float* eA = lgE + (p2 - 1) * 64;
                const float* oA = lgO + (p2 - 1) * 64;
                v0A = eA[l]; v1A = oA[l];
                vmA = (l > 0) ? oA[l - 1] : v0A;
            }
            const float* eB = lgE + p2 * 64;
            const float* oB = lgO + p2 * 64;
            const float v0B = eB[l], v1B = oB[l];
            const float vmB = (l > 0) ? oB[l - 1] : v0B;
            res = make_float4(0.25f * (vmA + v0A + vmB + v0B),
                              0.5f  * (v0A + v0B),
                              0.25f * (v0A + v1A + v0B + v1B),
                              0.5f  * (v1A + v1B));
        }
        *(float4*)(op + yl * 256 + 4 * l) = res;
    }
}

extern "C" void kernel_launch(void* const* d_in, const int* in_sizes, int n_in,
                              void* d_out, int out_size, void* d_ws, size_t ws_size,
                              hipStream_t stream) {
    (void)n_in; (void)out_size;
    const float* mask_feats  = (const float*)d_in[0];
    const float* mask_shift  = (const float*)d_in[1];
    const float* shifts      = (const float*)d_in[2];
    const float* inst_params = (const float*)d_in[3];
    const int*   im_inds     = (const int*)d_in[4];
    const int*   fpn_levels  = (const int*)d_in[5];
    float* out = (float*)d_out;
    float* rec = (float*)d_ws;

    const int n_inst = in_sizes[2] / 2;            // shifts is (n,2)
    const size_t rec_bytes = (size_t)4 * HW * 8 * sizeof(float);
    const int use_rec = (ws_size >= rec_bytes) ? 1 : 0;

    if (use_rec)
        pack_kernel<<<dim3(4 * HW / 256), dim3(256), 0, stream>>>(
            mask_feats, rec);

    dmh_kernel<<<dim3(n_inst * 8), dim3(256), 0, stream>>>(
        mask_feats, mask_shift, shifts, inst_params, im_inds, fpn_levels,
        rec, out, use_rec);
}